// Round 15
// baseline (128.322 us; speedup 1.0000x reference)
//
#include <hip/hip_runtime.h>

// CARAFE on MI355X. B=4, C=256, H=W=64, CMID=64, NK=100 (s=2, k=5).
// v10 = v9 with phase-1 A-staging ELIMINATED: MFMA A-fragments read directly from
//   w1c global (wave's 4 fragment addresses are 256B-contiguous, nq-waves identical
//   -> L1 broadcast; same pattern phase-2a already uses for w2c). Removes ACOPY +
//   wl0/wl1 (74KB LDS) + the vmcnt(0) barrier-drain of 36KB/c8 staging that was the
//   exposed serial cost (v9 post-mortem: conflict fix bought ~1us -> latency-bound).
//   With no global_load_lds left, ALL barriers are lgkmcnt-only: global loads/stores
//   pipeline across every phase boundary.
// LDS map (115968 B):
//   conv  : xs0@0(12800) xs1@12800(12800) fsb@25600(9216)
//   phase2: ls@34816(25600) red@60416(4096) kts@68608(25600)
//   phase3: tiles @0,@21760,@43520(ends 65280<68608 ok),@94208(ends 115968);
//           kts@68608..94208 untouched. Tiles 21760 B: [r5][g4][slotSW68][c4] f32.

#define BB 4
#define CC 256
#define HH 64
#define WW 64
#define CMID 64
#define NKCH 100

typedef __bf16 bf16;
typedef __bf16 bf16x8 __attribute__((ext_vector_type(8)));
typedef float f32x4 __attribute__((ext_vector_type(4)));

// lgkmcnt-only barrier: orders LDS ops; leaves global loads/stores in flight.
#define BAR_LGKM() asm volatile("s_waitcnt lgkmcnt(0)\n\ts_barrier" ::: "memory")

// ---- k0a: w1 -> w1c bf16 [c8][kk][q][oc][8]; block(0,0) also w2 -> w2c [kkq][oc112][8] ----
__global__ void k0a_transform(const float* __restrict__ w1, const float* __restrict__ w2,
                              bf16* __restrict__ w1c, bf16* __restrict__ w2c) {
    int c8 = blockIdx.x;          // 0..7
    int oq = blockIdx.y;          // 0..3
    int tid = threadIdx.x;
    __shared__ __align__(16) float wf[16 * 300];

    for (int i = tid; i < 16 * 72; i += 256) {
        int o = i / 72, r = i % 72;
        *(float4*)&wf[o * 300 + r * 4] =
            *(const float4*)&w1[(size_t)(oq * 16 + o) * 2304 + c8 * 288 + r * 4];
    }
    __syncthreads();

    for (int t = tid; t < 576; t += 256) {
        int o = t & 15, q = (t >> 4) & 3, kk = t >> 6;
        union { bf16 h[8]; uint4 u; } v;
        #pragma unroll
        for (int i8 = 0; i8 < 8; ++i8)
            v.h[i8] = (bf16)wf[o * 300 + (q * 8 + i8) * 9 + kk];
        *(uint4*)&w1c[(size_t)((((c8 * 9 + kk) * 4 + q) * 64) + oq * 16 + o) * 8] = v.u;
    }

    if (c8 == 0 && oq == 0) {     // w2c: A-image for the logits GEMM (oc padded to 112)
        for (int i = tid; i < 7168; i += 256) {
            int i8 = i & 7;
            int oc = (i >> 3) % 112;
            int kq = (i >> 3) / 112;          // kk*4+q, 0..7
            int ic = (kq >> 2) * 32 + (kq & 3) * 8 + i8;
            w2c[i] = (oc < NKCH) ? (bf16)w2[oc * 64 + ic] : (bf16)0.f;
        }
    }
}

// ---------------- k123: fused conv3x3+relu + conv1x1+softmax + reassembly ----------------
__global__ __launch_bounds__(512) void k123_fused(const float* __restrict__ x,
        const bf16* __restrict__ w1c, const bf16* __restrict__ w2c,
        const float* __restrict__ b1, const float* __restrict__ b2,
        float* __restrict__ out) {
    int bh = blockIdx.x;
    int b = bh >> 6, h = bh & 63;
    int tid = threadIdx.x;
    int lane = tid & 63, wid = tid >> 6;
    int l15 = lane & 15, quad = lane >> 4;
    int mhalf = wid & 1, nq = wid >> 1;

    __shared__ __align__(16) char smem[115968];
    bf16*  xs0  = (bf16*)smem;                   // [r3][g4][66][8] = 12672 B (pad 12800)
    bf16*  xs1  = (bf16*)(smem + 12800);
    bf16*  fsb  = (bf16*)(smem + 25600);         // [px64][ic] stride 72 bf16, 9216 B
    float* ls   = (float*)(smem + 34816);        // 25600 B
    float* red  = (float*)(smem + 60416);        // 4096 B
    float* kts  = (float*)(smem + 68608);        // 25600 B

    const float* xb = x + (size_t)b * (CC * HH * WW);

    // ---- phase 1: conv3x3 (256->64) + relu, pipelined MFMA; A direct from global ----
    int g0 = wid & 3, r0 = wid >> 2;
    bool tv1 = (wid < 4);
    int hr0 = h - 1 + r0;
    int hr1 = h + 1;
    bool vm0 = (hr0 >= 0 && hr0 < HH);
    bool vm1 = (hr1 < HH);

    float fA[16], fB[16];
    #define LOADX(C8, F)                                                          \
        {                                                                         \
            if (vm0) {                                                            \
                const float* s0 = xb + ((size_t)((C8) * 32 + g0 * 8) * (HH * WW)) \
                                 + hr0 * WW + lane;                               \
                _Pragma("unroll")                                                 \
                for (int i = 0; i < 8; ++i) F[i] = s0[(size_t)i * (HH * WW)];     \
            }                                                                     \
            if (tv1 && vm1) {                                                     \
                const float* s1 = xb + ((size_t)((C8) * 32 + g0 * 8) * (HH * WW)) \
                                 + hr1 * WW + lane;                               \
                _Pragma("unroll")                                                 \
                for (int i = 0; i < 8; ++i) F[8 + i] = s1[(size_t)i * (HH * WW)]; \
            }                                                                     \
        }
    #define WRITEB(F, XSDST)                                                      \
        {                                                                         \
            if (vm0) {                                                            \
                union { bf16 hh[8]; uint4 u; } cv;                                \
                _Pragma("unroll")                                                 \
                for (int i = 0; i < 8; ++i) cv.hh[i] = (bf16)F[i];                \
                *(uint4*)&(XSDST)[((r0 * 4 + g0) * 66 + 1 + lane) * 8] = cv.u;    \
            }                                                                     \
            if (tv1 && vm1) {                                                     \
                union { bf16 hh[8]; uint4 u; } cv;                                \
                _Pragma("unroll")                                                 \
                for (int i = 0; i < 8; ++i) cv.hh[i] = (bf16)F[8 + i];            \
                *(uint4*)&(XSDST)[((2 * 4 + g0) * 66 + 1 + lane) * 8] = cv.u;     \
            }                                                                     \
        }
    // A direct from w1c: wave reads 4 contiguous 256B blocks; nq-waves identical (L1 bcast)
    #define MFMAS(XSRC, C8)                                                       \
        _Pragma("unroll")                                                         \
        for (int kk = 0; kk < 9; ++kk) {                                          \
            int r3 = kk / 3, kw = kk % 3;                                         \
            const bf16* wp = w1c + ((size_t)((((C8) * 9 + kk) * 4 + quad) * 64    \
                                             + mhalf * 32 + l15) * 8);            \
            bf16x8 a0 = *(const bf16x8*)wp;                                       \
            bf16x8 a1 = *(const bf16x8*)(wp + 128);                               \
            bf16x8 xv = *(const bf16x8*)&(XSRC)[((r3 * 4 + quad) * 66 + nq * 16 + l15 + kw) * 8]; \
            acc0 = __builtin_amdgcn_mfma_f32_16x16x32_bf16(a0, xv, acc0, 0, 0, 0); \
            acc1 = __builtin_amdgcn_mfma_f32_16x16x32_bf16(a1, xv, acc1, 0, 0, 0); \
        }

    for (int i = tid; i < 6336; i += 512) { xs0[i] = (bf16)0.f; xs1[i] = (bf16)0.f; }
    LOADX(0, fA)
    BAR_LGKM();                   // zero-init visible
    WRITEB(fA, xs0)
    LOADX(1, fB)
    BAR_LGKM();                   // buf0 ready

    f32x4 acc0 = {0.f, 0.f, 0.f, 0.f}, acc1 = {0.f, 0.f, 0.f, 0.f};

    for (int c8 = 0; c8 < 8; c8 += 2) {
        if (c8 < 6) { LOADX(c8 + 2, fA) }
        MFMAS(xs0, c8)
        WRITEB(fB, xs1)
        BAR_LGKM();
        if (c8 < 6) { LOADX(c8 + 3, fB) }
        MFMAS(xs1, c8 + 1)
        if (c8 < 6) { WRITEB(fA, xs0) }
        BAR_LGKM();
    }

    // conv epilogue: bias+relu -> fsb bf16 [px][ic] stride 72
    int px = nq * 16 + l15;
    #pragma unroll
    for (int mi = 0; mi < 2; ++mi) {
        int oc0 = mhalf * 32 + mi * 16 + quad * 4;
        float4 bv = *(const float4*)&b1[oc0];
        f32x4 v = mi ? acc1 : acc0;
        union { bf16 hh[4]; unsigned long long u; } o;
        o.hh[0] = (bf16)fmaxf(v[0] + bv.x, 0.f);
        o.hh[1] = (bf16)fmaxf(v[1] + bv.y, 0.f);
        o.hh[2] = (bf16)fmaxf(v[2] + bv.z, 0.f);
        o.hh[3] = (bf16)fmaxf(v[3] + bv.w, 0.f);
        *(unsigned long long*)&fsb[px * 72 + oc0] = o.u;
    }
    BAR_LGKM();

    // ---- phase-3 identities + T14 pre-issue of pair-0 x tiles ----
    int t8 = tid & 255, h2 = tid >> 8;
    int w3 = t8 & 63, cg3 = t8 >> 6;
    #define XLOAD(P, V)                                                          \
        _Pragma("unroll")                                                        \
        for (int k = 0; k < 5; ++k) {                                            \
            int idx = t8 + k * 256;                                              \
            int u = idx & 15, cc = (idx >> 4) & 15, rr = idx >> 8;               \
            int hr = h - 2 + rr;                                                 \
            V[k] = make_float4(0.f, 0.f, 0.f, 0.f);                              \
            if (hr >= 0 && hr < HH)                                              \
                V[k] = *(const float4*)&x[(((size_t)b * CC + (2 * (P) + h2) * 16 + cc) * HH + hr) * WW + 4 * u]; \
        }
    #define XWRITE(V, TB)                                                        \
        _Pragma("unroll")                                                        \
        for (int k = 0; k < 5; ++k) {                                            \
            int idx = t8 + k * 256;                                              \
            int u = idx & 15, cc = (idx >> 4) & 15, rr = idx >> 8;               \
            int bse = (rr * 4 + (cc >> 2)) * 68;                                 \
            int c = cc & 3;                                                      \
            _Pragma("unroll")                                                    \
            for (int j = 0; j < 4; ++j) {                                        \
                int s = 2 + 4 * u + j;                                           \
                int sw = s ^ ((s >> 3) & 7);                                     \
                (TB)[(bse + sw) * 4 + c] = ((const float*)&V[k])[j];             \
            }                                                                    \
        }
    float4 xst[5];
    XLOAD(0, xst)

    // ---- phase 2a: conv1x1 logits via MFMA. A=w2c (global), B=fsb. D -> ls fp32 ----
    if (wid < 7) {
        f32x4 lacc0 = {0.f,0.f,0.f,0.f}, lacc1 = {0.f,0.f,0.f,0.f};
        f32x4 lacc2 = {0.f,0.f,0.f,0.f}, lacc3 = {0.f,0.f,0.f,0.f};
        #pragma unroll
        for (int kk = 0; kk < 2; ++kk) {
            bf16x8 a = *(const bf16x8*)&w2c[(((kk * 4 + quad) * 112) + wid * 16 + l15) * 8];
            bf16x8 bf0 = *(const bf16x8*)&fsb[( 0 + l15) * 72 + kk * 32 + quad * 8];
            bf16x8 bf1 = *(const bf16x8*)&fsb[(16 + l15) * 72 + kk * 32 + quad * 8];
            bf16x8 bf2 = *(const bf16x8*)&fsb[(32 + l15) * 72 + kk * 32 + quad * 8];
            bf16x8 bf3 = *(const bf16x8*)&fsb[(48 + l15) * 72 + kk * 32 + quad * 8];
            lacc0 = __builtin_amdgcn_mfma_f32_16x16x32_bf16(a, bf0, lacc0, 0, 0, 0);
            lacc1 = __builtin_amdgcn_mfma_f32_16x16x32_bf16(a, bf1, lacc1, 0, 0, 0);
            lacc2 = __builtin_amdgcn_mfma_f32_16x16x32_bf16(a, bf2, lacc2, 0, 0, 0);
            lacc3 = __builtin_amdgcn_mfma_f32_16x16x32_bf16(a, bf3, lacc3, 0, 0, 0);
        }
        f32x4 laccs[4] = {lacc0, lacc1, lacc2, lacc3};
        #pragma unroll
        for (int nt = 0; nt < 4; ++nt)
            #pragma unroll
            for (int j = 0; j < 4; ++j) {
                int oc = wid * 16 + quad * 4 + j;     // D row = oc, col(l15) = px
                if (oc < NKCH) ls[oc * 64 + nt * 16 + l15] = laccs[nt][j];
            }
    }
    BAR_LGKM();   // XLOAD(0) stays in flight

    // ---- phase 2b: softmax over FULL 100-channel dim (reads ls) ----
    int w = lane;
    int g = wid, s2 = g & 3, ihalf = g >> 2;
    int i0 = ihalf ? 13 : 0;

    float lg[13];
    #pragma unroll
    for (int ii = 0; ii < 13; ++ii) {
        int idx = i0 + ii;
        bool act = (idx < 25);
        int oc = s2 * 25 + (act ? idx : 0);
        lg[ii] = act ? (ls[oc * 64 + w] + b2[oc]) : -1e30f;
    }

    float m = -1e30f;
    #pragma unroll
    for (int ii = 0; ii < 13; ++ii) m = fmaxf(m, lg[ii]);
    red[g * 64 + w] = m;
    BAR_LGKM();
    m = fmaxf(fmaxf(fmaxf(red[0 * 64 + w], red[1 * 64 + w]),
                    fmaxf(red[2 * 64 + w], red[3 * 64 + w])),
              fmaxf(fmaxf(red[4 * 64 + w], red[5 * 64 + w]),
                    fmaxf(red[6 * 64 + w], red[7 * 64 + w])));
    float ssum = 0.f;
    #pragma unroll
    for (int ii = 0; ii < 13; ++ii) { lg[ii] = __expf(lg[ii] - m); ssum += lg[ii]; }
    red[512 + g * 64 + w] = ssum;
    BAR_LGKM();
    ssum = ((red[512 + 0 * 64 + w] + red[512 + 1 * 64 + w]) +
            (red[512 + 2 * 64 + w] + red[512 + 3 * 64 + w])) +
           ((red[512 + 4 * 64 + w] + red[512 + 5 * 64 + w]) +
            (red[512 + 6 * 64 + w] + red[512 + 7 * 64 + w]));
    float inv = 1.f / ssum;
    #pragma unroll
    for (int ii = 0; ii < 13; ++ii)
        if (i0 + ii < 25) kts[((i0 + ii) * 64 + w) * 4 + s2] = lg[ii] * inv;
    BAR_LGKM();   // kts visible; red/ls/xs/fsb now dead

    // ---- phase 3: reassembly + pixel shuffle, 2 chunks/iter, double-buffered tiles ----
    #pragma unroll
    for (int reg = 0; reg < 4; ++reg) {
        const int tb = (reg == 0) ? 0 : (reg == 1) ? 21760 : (reg == 2) ? 43520 : 94208;
        if (tid < 320) {
            int c = tid & 3, q = (tid >> 2) & 3, rg = tid >> 4;
            int slot = (q < 2) ? q : (q + 64);
            ((float*)(smem + tb))[(rg * 68 + slot) * 4 + c] = 0.f;
        }
    }

    float* tb0 = (float*)(smem + (h2 ? 21760 : 0));
    float* tb1 = (float*)(smem + (h2 ? 94208 : 43520));

    int swk[5];
    #pragma unroll
    for (int kw = 0; kw < 5; ++kw) {
        int s = w3 + kw;
        swk[kw] = s ^ ((s >> 3) & 7);
    }

    XWRITE(xst, tb0)
    BAR_LGKM();

    for (int p = 0; p < 8; ++p) {
        if (p < 7) { XLOAD(p + 1, xst) }       // T14: issue next pair's loads now
        float* T = (p & 1) ? tb1 : tb0;
        f32x4 a0 = {0.f,0.f,0.f,0.f}, a1 = {0.f,0.f,0.f,0.f};
        f32x4 a2 = {0.f,0.f,0.f,0.f}, a3 = {0.f,0.f,0.f,0.f};
        #pragma unroll
        for (int r = 0; r < 5; ++r) {
            #pragma unroll
            for (int kw = 0; kw < 5; ++kw) {
                f32x4 kvv = *(const f32x4*)&kts[((r * 5 + kw) * 64 + w3) * 4];
                f32x4 xv = *(const f32x4*)&T[((r * 4 + cg3) * 68 + swk[kw]) * 4];
                a0 += kvv.x * xv;
                a1 += kvv.y * xv;
                a2 += kvv.z * xv;
                a3 += kvv.w * xv;
            }
        }
        int cq = (2 * p + h2) * 4 + cg3;
        f32x4 accs[4] = {a0, a1, a2, a3};
        #pragma unroll
        for (int s = 0; s < 4; ++s) {
            size_t base = (((size_t)b * 256 + s * 64 + cq) * 128 + 2 * h) * 128 + 2 * w3;
            *(float2*)&out[base]       = make_float2(accs[s][0], accs[s][1]);
            *(float2*)&out[base + 128] = make_float2(accs[s][2], accs[s][3]);
        }
        if (p < 7) {
            float* Tnext = (p & 1) ? tb0 : tb1;
            XWRITE(xst, Tnext)
        }
        BAR_LGKM();   // out-stores stay in flight; kernel-end wait drains them
    }
    #undef LOADX
    #undef WRITEB
    #undef MFMAS
    #undef XLOAD
    #undef XWRITE
}

extern "C" void kernel_launch(void* const* d_in, const int* in_sizes, int n_in,
                              void* d_out, int out_size, void* d_ws, size_t ws_size,
                              hipStream_t stream) {
    const float* x  = (const float*)d_in[0];
    const float* w1 = (const float*)d_in[1];
    const float* b1 = (const float*)d_in[2];
    const float* w2 = (const float*)d_in[3];
    const float* b2 = (const float*)d_in[4];
    float* out = (float*)d_out;

    char* wsb = (char*)d_ws;
    bf16* w1c = (bf16*)wsb;                      // 294,912 B
    bf16* w2c = (bf16*)(wsb + 294912);           // 14,336 B

    k0a_transform<<<dim3(8, 4), 256, 0, stream>>>(w1, w2, w1c, w2c);
    k123_fused<<<dim3(BB * HH), 512, 0, stream>>>(x, w1c, w2c, b1, b2, out);
}